// Round 13
// baseline (207.436 us; speedup 1.0000x reference)
//
#include <hip/hip_runtime.h>
#include <stdint.h>

#define B_     4
#define A_     9
#define H_     50
#define W_     76
#define HW_    (H_ * W_)         // 3800
#define N_     (HW_ * A_)        // 34200
#define PRE_   6000
#define POST_  300
#define NBIN   16384
#define BINOFF 0xC000
#define SKCAP  8192
#define ACTMAX 256
#define FXCAP  2048
#define WSZ    512
#define NSB    8                 // 64-wide sub-blocks per window
#define NWIN   ((PRE_ + WSZ - 1) / WSZ)   // 12
#define NTASK  36                // NSB*(NSB+1)/2 mask sub-tiles per window

// generate_anchors(16) precomputed (exact, verified against the numpy code)
__constant__ float c_anchors[9][4] = {
    { -84.f,  -40.f,  99.f,  55.f},
    {-176.f,  -88.f, 191.f, 103.f},
    {-360.f, -184.f, 375.f, 199.f},
    { -56.f,  -56.f,  71.f,  71.f},
    {-120.f, -120.f, 135.f, 135.f},
    {-248.f, -248.f, 263.f, 263.f},
    { -36.f,  -80.f,  51.f,  95.f},
    { -80.f, -168.f,  95.f, 183.f},
    {-168.f, -344.f, 183.f, 359.f},
};

// scores in [0,1) -> bin = top16(~score_bits) - 0xC000, clamped (monotone; exactness is
// restored by full-key rank within bucket in k_fixup).
__device__ __forceinline__ int sb_bin(unsigned int sb) {
    int bin = (int)((~sb) >> 16) - BINOFF;
    return bin < 0 ? 0 : bin;
}

// ---- kernel 1: histogram of score bins (direct coalesced score reads)
__global__ void k_hist(const float* __restrict__ scores,
                       unsigned int* __restrict__ hist) {
    int b = blockIdx.y;
    int i = blockIdx.x * 256 + threadIdx.x;
    if (i >= N_) return;
    const float* sc = scores + (size_t)((b * 2 * A_) + A_) * HW_;
    unsigned int sb = __float_as_uint(sc[i]);
    atomicAdd(&hist[b * NBIN + sb_bin(sb)], 1u);
}

// ---- kernel 2: full 16384-bin exclusive prefix in ONE block/image (coalesced uint4)
__global__ __launch_bounds__(1024) void k_prefix(unsigned int* __restrict__ hist,
                                                 unsigned int* __restrict__ prefw,
                                                 unsigned int* __restrict__ actA,
                                                 unsigned int* __restrict__ actB,
                                                 unsigned int* __restrict__ actcnt) {
    int b = blockIdx.x, tid = threadIdx.x;
    int lane = tid & 63, wid = tid >> 6;
    __shared__ unsigned int s_ws[64];
    __shared__ unsigned int s_aA[ACTMAX];
    __shared__ unsigned int s_aB[ACTMAX];
    __shared__ int s_actn;
    if (tid == 0) s_actn = 0;

    uint4* h4 = (uint4*)(hist + b * NBIN);
    uint4* p4 = (uint4*)(prefw + b * NBIN);
    uint4 c[4];
    unsigned int tsum[4], inc[4];
#pragma unroll
    for (int p = 0; p < 4; ++p) {
        c[p] = h4[p * 1024 + tid];
        tsum[p] = c[p].x + c[p].y + c[p].z + c[p].w;
        unsigned int v = tsum[p];
#pragma unroll
        for (int off = 1; off < 64; off <<= 1) {
            unsigned int t = __shfl_up(v, off);
            if (lane >= off) v += t;
        }
        inc[p] = v;
        if (lane == 63) s_ws[p * 16 + wid] = v;
    }
    __syncthreads();
    if (wid == 0) {
        unsigned int v = s_ws[lane];
        unsigned int s = v;
#pragma unroll
        for (int off = 1; off < 64; off <<= 1) {
            unsigned int t = __shfl_up(s, off);
            if (lane >= off) s += t;
        }
        s_ws[lane] = s - v;
    }
    __syncthreads();
#pragma unroll
    for (int p = 0; p < 4; ++p) {
        unsigned int base = s_ws[p * 16 + wid] + inc[p] - tsum[p];
        uint4 r;
        r.x = base;
        r.y = base + c[p].x;
        r.z = r.y + c[p].y;
        r.w = r.z + c[p].z;
        h4[p * 1024 + tid] = r;
        p4[p * 1024 + tid] = r;
        unsigned int cc[4] = {c[p].x, c[p].y, c[p].z, c[p].w};
        unsigned int rr[4] = {r.x, r.y, r.z, r.w};
        int bin0 = (p * 1024 + tid) * 4;
#pragma unroll
        for (int q = 0; q < 4; ++q) {
            if (cc[q] > 0 && rr[q] < (unsigned int)PRE_) {
                int pos = atomicAdd(&s_actn, 1);
                if (pos < ACTMAX) {
                    s_aA[pos] = rr[q];
                    s_aB[pos] = ((unsigned int)(bin0 + q) << 16) | (cc[q] & 0xffffu);
                }
            }
        }
    }
    __syncthreads();
    int n = s_actn; if (n > ACTMAX) n = ACTMAX;
    for (int i = tid; i < n; i += 1024) {
        actA[b * ACTMAX + i] = s_aA[i];
        actB[b * ACTMAX + i] = s_aB[i];
    }
    if (tid == 0) actcnt[b] = (unsigned int)n;
}

// ---- kernel 3: scatter keys of active buckets to their slot range (arrival order)
__global__ void k_scatter(const float* __restrict__ scores,
                          const unsigned int* __restrict__ hist,
                          unsigned int* __restrict__ prefw,
                          unsigned long long* __restrict__ skeys) {
    int b = blockIdx.y;
    int i = blockIdx.x * 256 + threadIdx.x;
    if (i >= N_) return;
    const float* sc = scores + (size_t)((b * 2 * A_) + A_) * HW_;
    unsigned int sb = __float_as_uint(sc[i]);
    int bin = sb_bin(sb);
    if (hist[b * NBIN + bin] < (unsigned int)PRE_) {
        unsigned int slot = atomicAdd(&prefw[b * NBIN + bin], 1u);
        if (slot < SKCAP) {
            int a = i / HW_, r = i - a * HW_;
            unsigned int n = (unsigned int)(r * A_ + a);
            skeys[b * SKCAP + slot] =
                (((unsigned long long)(~sb)) << 32) | (unsigned long long)n;
        }
    }
}

// box decode exactly in the reference op order; no FMA contraction
__device__ __forceinline__ void compute_box(int b, unsigned int n,
                                            const float* __restrict__ deltas,
                                            const float* __restrict__ im_info,
                                            float box[4]) {
#pragma clang fp contract(off)
    int a   = (int)(n % A_);
    int pos = (int)(n / A_);
    int w   = pos % W_;
    int h   = pos / W_;
    float a0 = c_anchors[a][0] + (float)(w * 16);
    float a1 = c_anchors[a][1] + (float)(h * 16);
    float a2 = c_anchors[a][2] + (float)(w * 16);
    float a3 = c_anchors[a][3] + (float)(h * 16);
    float wa  = a2 - a0 + 1.f;
    float ha  = a3 - a1 + 1.f;
    float cxa = a0 + 0.5f * wa;
    float cya = a1 + 0.5f * ha;
    int base = ((b * 4 * A_ + a * 4) * H_ + h) * W_ + w;
    const int chs = HW_;
    float dx = deltas[base];
    float dy = deltas[base + chs];
    float dw = deltas[base + 2 * chs];
    float dh = deltas[base + 3 * chs];
    float pcx = dx * wa + cxa;
    float pcy = dy * ha + cya;
    float pw  = expf(dw) * wa;
    float ph  = expf(dh) * ha;
    float x1 = pcx - 0.5f * pw;
    float y1 = pcy - 0.5f * ph;
    float x2 = pcx + 0.5f * pw;
    float y2 = pcy + 0.5f * ph;
    float imh = im_info[b * 3 + 0], imw = im_info[b * 3 + 1];
    x1 = fminf(fmaxf(x1, 0.f), imw - 1.f);
    x2 = fminf(fmaxf(x2, 0.f), imw - 1.f);
    y1 = fminf(fmaxf(y1, 0.f), imh - 1.f);
    y2 = fminf(fmaxf(y2, 0.f), imh - 1.f);
    box[0] = x1; box[1] = y1; box[2] = x2; box[3] = y2;
}

// ---- kernel 4: per-bucket exact rank-by-counting + box decode into final sorted slot
__global__ __launch_bounds__(256) void k_fixup(const unsigned long long* __restrict__ skeys,
                                               const unsigned int* __restrict__ actA,
                                               const unsigned int* __restrict__ actB,
                                               const unsigned int* __restrict__ actcnt,
                                               const float* __restrict__ deltas,
                                               const float* __restrict__ im_info,
                                               float* __restrict__ sboxes) {
    int b = blockIdx.y;
    unsigned int nact = actcnt[b];
    if (nact > ACTMAX) nact = ACTMAX;
    if (blockIdx.x >= nact) return;
    int tid = threadIdx.x;
    unsigned int start = actA[b * ACTMAX + blockIdx.x];
    unsigned int ab    = actB[b * ACTMAX + blockIdx.x];
    unsigned int cnt   = ab & 0xffffu;
    unsigned int m = cnt;
    if (start + m > SKCAP) m = SKCAP - start;
    if (m > FXCAP) m = FXCAP;
    __shared__ unsigned long long lk[FXCAP];   // 16 KB
    for (unsigned int i = tid; i < m; i += 256) lk[i] = skeys[b * SKCAP + start + i];
    __syncthreads();
    float4* sb4 = (float4*)sboxes;
    for (unsigned int e = tid; e < m; e += 256) {
        unsigned long long k = lk[e];
        unsigned int r = 0;
        for (unsigned int i = 0; i < m; ++i) r += (lk[i] < k) ? 1u : 0u;
        unsigned int pos = start + r;
        if (pos < (unsigned int)PRE_) {
            unsigned int n = (unsigned int)(k & 0xffffffffull);
            float box[4];
            compute_box(b, n, deltas, im_info, box);
            sb4[b * PRE_ + pos] = make_float4(box[0], box[1], box[2], box[3]);
        }
    }
}

__device__ __forceinline__ bool iou_gt(float4 p, float pa, float4 q, float qa) {
    float iw = fminf(p.z, q.z) - fmaxf(p.x, q.x) + 1.f;
    float ih = fminf(p.w, q.w) - fmaxf(p.y, q.y) + 1.f;
    iw = fmaxf(iw, 0.f); ih = fmaxf(ih, 0.f);
    float inter = iw * ih;
    float iou = inter / ((pa + qa) - inter);
    return iou > 0.7f;
}

// map task index t (0..35) -> sub-block pair (si <= sj)
__device__ __forceinline__ void task_pair(int t, int* si, int* sj) {
    int s = 0, rem = t;
    while (rem >= NSB - s) { rem -= NSB - s; ++s; }
    *si = s; *sj = s + rem;
}

// compute one 64x64 suppression sub-tile of window w into LDS mask buffer.
// wm[row][word]: bit (word*64+c) = "window-candidate row is kept => suppresses c".
__device__ __forceinline__ void mask_task(const float4* __restrict__ bb, int w,
                                          int si, int sj, int lane,
                                          unsigned long long (*wm)[NSB]) {
    int gi = w * WSZ + si * 64 + lane;
    int gj = w * WSZ + sj * 64 + lane;
    float4 vi = bb[gi < PRE_ ? gi : PRE_ - 1];
    float ai = ((vi.z - vi.x) + 1.f) * ((vi.w - vi.y) + 1.f);
    float4 vj; float aj;
    if (si == sj) { vj = vi; aj = ai; }
    else {
        vj = bb[gj < PRE_ ? gj : PRE_ - 1];
        aj = ((vj.z - vj.x) + 1.f) * ((vj.w - vj.y) + 1.f);
    }
    for (int i = 0; i < 64; ++i) {
        float4 p;
        p.x = __shfl(vi.x, i); p.y = __shfl(vi.y, i);
        p.z = __shfl(vi.z, i); p.w = __shfl(vi.w, i);
        float pa = __shfl(ai, i);
        bool hit = iou_gt(p, pa, vj, aj);
        if (si == sj) hit = hit && (lane > i);
        unsigned long long bal = __ballot(hit);
        if (lane == i) wm[si * 64 + i][sj] = bal;
    }
    if (si == sj) {   // zero the lower words of this sub-block's rows
        for (int q = 0; q < si; ++q) wm[si * 64 + lane][q] = 0ull;
    }
}

// ---- kernel 5: exact greedy NMS in 512-candidate windows.
//      per window: phase A (all waves: vs kept list) -> barrier ->
//      wave 0 mask-only resolve of window w  ||  waves 1-15 build masks for w+1
//      -> barrier. Masks double-buffered in LDS. 2 barriers/window.
__global__ __launch_bounds__(1024) void k_nms(const float* __restrict__ sboxes,
                                              float* __restrict__ out) {
    int b = blockIdx.x;
    int tid = threadIdx.x;
    int lane = tid & 63;
    int wid = tid >> 6;                        // 0..15
    __shared__ unsigned long long wmask[2][WSZ][NSB];   // 64 KB
    __shared__ float4 s_wbox[WSZ];                      // 8 KB
    __shared__ float  s_war [WSZ];                      // 2 KB
    __shared__ float4 s_box[POST_];
    __shared__ float  s_ar [POST_];
    __shared__ unsigned long long s_supw[2][NSB];
    __shared__ int s_cnt;
    if (tid == 0) s_cnt = 0;

    const float4* bb = (const float4*)sboxes + b * PRE_;
    float* ob = out + b * POST_ * 5;

    const int c = tid & (WSZ - 1);             // candidate-in-window
    const int h = tid >> 9;                    // 0/1: kept-list half

    // prologue: masks for window 0 (all 16 waves) + prefetch window-0 boxes
    for (int t = wid; t < NTASK; t += 16) {
        int si, sj; task_pair(t, &si, &sj);
        mask_task(bb, 0, si, sj, lane, wmask[0]);
    }
    int idx0 = c;                              // window 0 candidate index
    float4 vreg = bb[idx0 < PRE_ ? idx0 : PRE_ - 1];
    __syncthreads();

    for (int w = 0; w < NWIN; ++w) {
        int C = s_cnt;                         // uniform (post-barrier)
        if (C >= POST_) break;

        // ---- phase A: window-w candidates vs kept[0..C), 2 threads/candidate
        int idx = w * WSZ + c;
        bool valid = idx < PRE_;
        float4 v = vreg;
        // prefetch next window's candidate box (latency hidden across intervals)
        if (w + 1 < NWIN) {
            int nidx = (w + 1) * WSZ + c;
            vreg = bb[nidx < PRE_ ? nidx : PRE_ - 1];
        }
        float area = ((v.z - v.x) + 1.f) * ((v.w - v.y) + 1.f);
        if (h == 0) { s_wbox[c] = v; s_war[c] = area; }
        bool sup = !valid;
        int kk = h;
        for (; kk + 6 < C; kk += 8) {          // stride 2, unrolled 4
            float4 k0 = s_box[kk],     k1 = s_box[kk + 2];
            float4 k2 = s_box[kk + 4], k3 = s_box[kk + 6];
            float  r0 = s_ar [kk],     r1 = s_ar [kk + 2];
            float  r2 = s_ar [kk + 4], r3 = s_ar [kk + 6];
            sup = sup | iou_gt(v, area, k0, r0) | iou_gt(v, area, k1, r1)
                      | iou_gt(v, area, k2, r2) | iou_gt(v, area, k3, r3);
        }
        for (; kk < C; kk += 2)
            sup = sup | iou_gt(v, area, s_box[kk], s_ar[kk]);
        unsigned long long bal = __ballot(sup);
        if (lane == 0) s_supw[h][wid & 7] = bal;
        __syncthreads();

        // ---- interval 2: wave0 resolves w; waves 1-15 build masks for w+1
        if (wid == 0) {
            unsigned long long alive = 0ull;
            if (lane < NSB) alive = ~(s_supw[0][lane] | s_supw[1][lane]);
            unsigned long long (*wm)[NSB] = wmask[w & 1];
            int nk = 0;
            while (true) {
                int first = WSZ;
                if (lane < NSB && alive) first = __builtin_ctzll(alive) + lane * 64;
#pragma unroll
                for (int off = 4; off > 0; off >>= 1)
                    first = min(first, __shfl_xor(first, off));
                first = __shfl(first, 0);
                if (first >= WSZ) break;
                int pos = C + nk;
                float4 kb = s_wbox[first];     // broadcast LDS read
                float  ka = s_war [first];
                if (lane == 0) {
                    s_box[pos] = kb; s_ar[pos] = ka;
                    ob[pos * 5 + 0] = (float)b;
                    ob[pos * 5 + 1] = kb.x; ob[pos * 5 + 2] = kb.y;
                    ob[pos * 5 + 3] = kb.z; ob[pos * 5 + 4] = kb.w;
                }
                ++nk;
                if (pos + 1 >= POST_) break;
                if (lane < NSB) {
                    alive &= ~wm[first][lane];
                    if ((first >> 6) == lane) alive &= ~(1ull << (first & 63));
                }
            }
            if (lane == 0) s_cnt = C + nk;
        } else if (w + 1 < NWIN) {
            for (int t = wid - 1; t < NTASK; t += 15) {
                int si, sj; task_pair(t, &si, &sj);
                mask_task(bb, w + 1, si, sj, lane, wmask[(w + 1) & 1]);
            }
        }
        __syncthreads();
    }

    // zero-fill rows beyond the kept count
    int kept = s_cnt;
    int start = kept < POST_ ? kept : POST_;
    for (int r = start + tid; r < POST_; r += 1024) {
        ob[r * 5 + 0] = (float)b;
        ob[r * 5 + 1] = 0.f; ob[r * 5 + 2] = 0.f;
        ob[r * 5 + 3] = 0.f; ob[r * 5 + 4] = 0.f;
    }
}

extern "C" void kernel_launch(void* const* d_in, const int* in_sizes, int n_in,
                              void* d_out, int out_size, void* d_ws, size_t ws_size,
                              hipStream_t stream) {
    const float* scores  = (const float*)d_in[0];
    const float* deltas  = (const float*)d_in[1];
    const float* im_info = (const float*)d_in[2];
    float* out = (float*)d_out;

    char* ws = (char*)d_ws;
    unsigned int*       hist    = (unsigned int*)      (ws);             // 262,144
    unsigned int*       prefw   = (unsigned int*)      (ws + 262144);    // 262,144
    unsigned long long* skeys   = (unsigned long long*)(ws + 524288);    // 262,144
    unsigned int*       actA    = (unsigned int*)      (ws + 786432);    //   4,096
    unsigned int*       actB    = (unsigned int*)      (ws + 790528);    //   4,096
    unsigned int*       actcnt  = (unsigned int*)      (ws + 794624);    //      32
    float*              sbx     = (float*)             (ws + 794656);    // 384,000

    hipMemsetAsync(hist, 0, B_ * NBIN * sizeof(unsigned int), stream);

    dim3 g2d((N_ + 255) / 256, B_);
    k_hist<<<g2d, 256, 0, stream>>>(scores, hist);
    k_prefix<<<B_, 1024, 0, stream>>>(hist, prefw, actA, actB, actcnt);
    k_scatter<<<g2d, 256, 0, stream>>>(scores, hist, prefw, skeys);
    dim3 fgrid(ACTMAX, B_);
    k_fixup<<<fgrid, 256, 0, stream>>>(skeys, actA, actB, actcnt, deltas, im_info, sbx);
    k_nms<<<B_, 1024, 0, stream>>>(sbx, out);
}

// Round 14
// 90.437 us; speedup vs baseline: 2.2937x; 2.2937x over previous
//
#include <hip/hip_runtime.h>
#include <stdint.h>

#define B_     4
#define A_     9
#define H_     50
#define W_     76
#define HW_    (H_ * W_)         // 3800
#define N_     (HW_ * A_)        // 34200
#define PRE_   6000
#define POST_  300
#define NBIN   16384
#define BINOFF 0xC000
#define SKCAP  8192
#define ACTMAX 256
#define FXCAP  2048
#define NB_    94               // ceil(PRE_/64)

// generate_anchors(16) precomputed (exact, verified against the numpy code)
__constant__ float c_anchors[9][4] = {
    { -84.f,  -40.f,  99.f,  55.f},
    {-176.f,  -88.f, 191.f, 103.f},
    {-360.f, -184.f, 375.f, 199.f},
    { -56.f,  -56.f,  71.f,  71.f},
    {-120.f, -120.f, 135.f, 135.f},
    {-248.f, -248.f, 263.f, 263.f},
    { -36.f,  -80.f,  51.f,  95.f},
    { -80.f, -168.f,  95.f, 183.f},
    {-168.f, -344.f, 183.f, 359.f},
};

// scores in [0,1) -> bin = top16(~score_bits) - 0xC000, clamped (monotone; exactness is
// restored by full-key rank within bucket in k_fixup).
__device__ __forceinline__ int sb_bin(unsigned int sb) {
    int bin = (int)((~sb) >> 16) - BINOFF;
    return bin < 0 ? 0 : bin;
}

// ---- kernel 1: fused LDS histogram + full 16384-bin exclusive prefix, 1 block/image.
//      No global-hist pre-zero needed (LDS hist zeroed in-kernel); writes static prefix
//      (hist), working prefix (prefw), active buckets, actcnt.
__global__ __launch_bounds__(1024) void k_hp(const float* __restrict__ scores,
                                             unsigned int* __restrict__ hist,
                                             unsigned int* __restrict__ prefw,
                                             unsigned int* __restrict__ actA,
                                             unsigned int* __restrict__ actB,
                                             unsigned int* __restrict__ actcnt) {
    int b = blockIdx.x, tid = threadIdx.x;
    int lane = tid & 63, wid = tid >> 6;
    __shared__ unsigned int s_hist[NBIN];   // 64 KB
    __shared__ unsigned int s_ws[64];       // (pass,wave) totals, bin-order p*16+wid
    __shared__ unsigned int s_aA[ACTMAX];
    __shared__ unsigned int s_aB[ACTMAX];
    __shared__ int s_actn;
    if (tid == 0) s_actn = 0;
    for (int i = tid; i < NBIN; i += 1024) s_hist[i] = 0u;
    __syncthreads();

    // LDS histogram (coalesced score reads; bins spread over 16384 -> low conflict)
    const float* sc = scores + (size_t)((b * 2 * A_) + A_) * HW_;
    for (int i = tid; i < N_; i += 1024) {
        unsigned int sb = __float_as_uint(sc[i]);
        atomicAdd(&s_hist[sb_bin(sb)], 1u);
    }
    __syncthreads();

    // exclusive prefix over 16384 bins (round-12 uint4 two-level shfl scan, LDS source)
    uint4* h4 = (uint4*)(hist + b * NBIN);
    uint4* p4 = (uint4*)(prefw + b * NBIN);
    const uint4* s4 = (const uint4*)s_hist;
    uint4 c[4];
    unsigned int tsum[4], inc[4];
#pragma unroll
    for (int p = 0; p < 4; ++p) {
        c[p] = s4[p * 1024 + tid];
        tsum[p] = c[p].x + c[p].y + c[p].z + c[p].w;
        unsigned int v = tsum[p];
#pragma unroll
        for (int off = 1; off < 64; off <<= 1) {
            unsigned int t = __shfl_up(v, off);
            if (lane >= off) v += t;
        }
        inc[p] = v;                          // wave-inclusive scan of tsum
        if (lane == 63) s_ws[p * 16 + wid] = v;
    }
    __syncthreads();
    if (wid == 0) {                          // exclusive scan of the 64 totals
        unsigned int v = s_ws[lane];
        unsigned int s = v;
#pragma unroll
        for (int off = 1; off < 64; off <<= 1) {
            unsigned int t = __shfl_up(s, off);
            if (lane >= off) s += t;
        }
        s_ws[lane] = s - v;
    }
    __syncthreads();
#pragma unroll
    for (int p = 0; p < 4; ++p) {
        unsigned int base = s_ws[p * 16 + wid] + inc[p] - tsum[p];
        uint4 r;
        r.x = base;
        r.y = base + c[p].x;
        r.z = r.y + c[p].y;
        r.w = r.z + c[p].z;
        h4[p * 1024 + tid] = r;              // static prefix (coalesced)
        p4[p * 1024 + tid] = r;              // working prefix (coalesced)
        unsigned int cc[4] = {c[p].x, c[p].y, c[p].z, c[p].w};
        unsigned int rr[4] = {r.x, r.y, r.z, r.w};
        int bin0 = (p * 1024 + tid) * 4;
#pragma unroll
        for (int q = 0; q < 4; ++q) {
            if (cc[q] > 0 && rr[q] < (unsigned int)PRE_) {
                int pos = atomicAdd(&s_actn, 1);
                if (pos < ACTMAX) {
                    s_aA[pos] = rr[q];
                    s_aB[pos] = ((unsigned int)(bin0 + q) << 16) | (cc[q] & 0xffffu);
                }
            }
        }
    }
    __syncthreads();
    int n = s_actn; if (n > ACTMAX) n = ACTMAX;
    for (int i = tid; i < n; i += 1024) {
        actA[b * ACTMAX + i] = s_aA[i];
        actB[b * ACTMAX + i] = s_aB[i];
    }
    if (tid == 0) actcnt[b] = (unsigned int)n;
}

// ---- kernel 2: scatter keys of active buckets to their slot range (arrival order)
__global__ void k_scatter(const float* __restrict__ scores,
                          const unsigned int* __restrict__ hist,   // static prefix
                          unsigned int* __restrict__ prefw,        // working prefix
                          unsigned long long* __restrict__ skeys) {
    int b = blockIdx.y;
    int i = blockIdx.x * 256 + threadIdx.x;
    if (i >= N_) return;
    const float* sc = scores + (size_t)((b * 2 * A_) + A_) * HW_;
    unsigned int sb = __float_as_uint(sc[i]);
    int bin = sb_bin(sb);
    if (hist[b * NBIN + bin] < (unsigned int)PRE_) {
        unsigned int slot = atomicAdd(&prefw[b * NBIN + bin], 1u);
        if (slot < SKCAP) {
            int a = i / HW_, r = i - a * HW_;
            unsigned int n = (unsigned int)(r * A_ + a);
            skeys[b * SKCAP + slot] =
                (((unsigned long long)(~sb)) << 32) | (unsigned long long)n;
        }
    }
}

// box decode exactly in the reference op order; no FMA contraction
__device__ __forceinline__ void compute_box(int b, unsigned int n,
                                            const float* __restrict__ deltas,
                                            const float* __restrict__ im_info,
                                            float box[4]) {
#pragma clang fp contract(off)
    int a   = (int)(n % A_);
    int pos = (int)(n / A_);
    int w   = pos % W_;
    int h   = pos / W_;
    float a0 = c_anchors[a][0] + (float)(w * 16);
    float a1 = c_anchors[a][1] + (float)(h * 16);
    float a2 = c_anchors[a][2] + (float)(w * 16);
    float a3 = c_anchors[a][3] + (float)(h * 16);
    float wa  = a2 - a0 + 1.f;
    float ha  = a3 - a1 + 1.f;
    float cxa = a0 + 0.5f * wa;
    float cya = a1 + 0.5f * ha;
    int base = ((b * 4 * A_ + a * 4) * H_ + h) * W_ + w;
    const int chs = HW_;
    float dx = deltas[base];
    float dy = deltas[base + chs];
    float dw = deltas[base + 2 * chs];
    float dh = deltas[base + 3 * chs];
    float pcx = dx * wa + cxa;
    float pcy = dy * ha + cya;
    float pw  = expf(dw) * wa;
    float ph  = expf(dh) * ha;
    float x1 = pcx - 0.5f * pw;
    float y1 = pcy - 0.5f * ph;
    float x2 = pcx + 0.5f * pw;
    float y2 = pcy + 0.5f * ph;
    float imh = im_info[b * 3 + 0], imw = im_info[b * 3 + 1];
    x1 = fminf(fmaxf(x1, 0.f), imw - 1.f);
    x2 = fminf(fmaxf(x2, 0.f), imw - 1.f);
    y1 = fminf(fmaxf(y1, 0.f), imh - 1.f);
    y2 = fminf(fmaxf(y2, 0.f), imh - 1.f);
    box[0] = x1; box[1] = y1; box[2] = x2; box[3] = y2;
}

// ---- kernel 3: per-bucket exact rank-by-counting + box decode into final sorted slot
__global__ __launch_bounds__(256) void k_fixup(const unsigned long long* __restrict__ skeys,
                                               const unsigned int* __restrict__ actA,
                                               const unsigned int* __restrict__ actB,
                                               const unsigned int* __restrict__ actcnt,
                                               const float* __restrict__ deltas,
                                               const float* __restrict__ im_info,
                                               float* __restrict__ sboxes) {
    int b = blockIdx.y;
    unsigned int nact = actcnt[b];
    if (nact > ACTMAX) nact = ACTMAX;
    if (blockIdx.x >= nact) return;
    int tid = threadIdx.x;
    unsigned int start = actA[b * ACTMAX + blockIdx.x];
    unsigned int ab    = actB[b * ACTMAX + blockIdx.x];
    unsigned int cnt   = ab & 0xffffu;
    unsigned int m = cnt;
    if (start + m > SKCAP) m = SKCAP - start;
    if (m > FXCAP) m = FXCAP;
    __shared__ unsigned long long lk[FXCAP];   // 16 KB
    for (unsigned int i = tid; i < m; i += 256) lk[i] = skeys[b * SKCAP + start + i];
    __syncthreads();
    float4* sb4 = (float4*)sboxes;
    for (unsigned int e = tid; e < m; e += 256) {
        unsigned long long k = lk[e];
        unsigned int r = 0;
        for (unsigned int i = 0; i < m; ++i) r += (lk[i] < k) ? 1u : 0u;
        unsigned int pos = start + r;
        if (pos < (unsigned int)PRE_) {
            unsigned int n = (unsigned int)(k & 0xffffffffull);
            float box[4];
            compute_box(b, n, deltas, im_info, box);
            sb4[b * PRE_ + pos] = make_float4(box[0], box[1], box[2], box[3]);
        }
    }
}

__device__ __forceinline__ bool iou_gt(float4 p, float pa, float4 q, float qa) {
    float iw = fminf(p.z, q.z) - fmaxf(p.x, q.x) + 1.f;
    float ih = fminf(p.w, q.w) - fmaxf(p.y, q.y) + 1.f;
    iw = fmaxf(iw, 0.f); ih = fmaxf(ih, 0.f);
    float inter = iw * ih;
    float iou = inter / ((pa + qa) - inter);
    return iou > 0.7f;
}

// ---- kernel 4: per-block 64x64 intra-block suppression masks (fully parallel)
__global__ __launch_bounds__(64) void k_mask(const float* __restrict__ sboxes,
                                             unsigned long long* __restrict__ mask) {
    int b = blockIdx.y, blk = blockIdx.x;
    int lane = threadIdx.x;
    const float4* bb = (const float4*)sboxes + b * PRE_;
    int idx = blk * 64 + lane;
    float4 v = bb[idx < PRE_ ? idx : PRE_ - 1];
    float area = ((v.z - v.x) + 1.f) * ((v.w - v.y) + 1.f);
    unsigned long long myrow = 0ull;
    for (int i = 0; i < 64; ++i) {
        float4 p;
        p.x = __shfl(v.x, i); p.y = __shfl(v.y, i);
        p.z = __shfl(v.z, i); p.w = __shfl(v.w, i);
        float pa = __shfl(area, i);
        unsigned long long bal = __ballot((lane > i) && iou_gt(p, pa, v, area));
        if (lane == i) myrow = bal;
    }
    mask[(b * NB_ + blk) * 64 + lane] = myrow;
}

// ---- kernel 5: exact greedy NMS, pipelined (round-7 structure), phase-a unrolled x4
__global__ __launch_bounds__(1024) void k_nms(const float* __restrict__ sboxes,
                                              const unsigned long long* __restrict__ mask,
                                              float* __restrict__ out) {
    int b = blockIdx.x;
    int tid = threadIdx.x;
    int lane = tid & 63;
    int wave = tid >> 6;                     // 0..15
    __shared__ float4 s_box[POST_ + 64];
    __shared__ float  s_ar [POST_ + 64];
    __shared__ unsigned long long s_pend[2][16];
    __shared__ int s_cnt[2];
    __shared__ int s_final;
    if (tid < 32) ((unsigned long long*)s_pend)[tid] = 0ull;
    if (tid < 2) s_cnt[tid] = 0;
    if (tid == 0) s_final = 0;
    __syncthreads();

    const float4* bb = (const float4*)sboxes + b * PRE_;
    float* ob = out + b * POST_ * 5;

    // register prefetch: wave0 holds block 0 (+mask row); waves 1-15 hold block 1
    float4 vme;
    unsigned long long rowme = 0ull;
    if (wave == 0) {
        vme = bb[lane];
        rowme = mask[(b * NB_ + 0) * 64 + lane];
    } else {
        vme = bb[64 + lane];
    }

    for (int k = 0; k < NB_; ++k) {
        int Cm1 = s_cnt[(k + 1) & 1];         // kept count through block k-1
        if (Cm1 >= POST_) break;
        if (wave == 0) {
            int idx = k * 64 + lane;
            bool valid = idx < PRE_;
            float4 v = vme;
            unsigned long long row = rowme;
            if (k + 1 < NB_) {                 // prefetch block k+1
                int nidx = (k + 1) * 64 + lane;
                vme = bb[nidx < PRE_ ? nidx : PRE_ - 1];
                rowme = mask[(b * NB_ + k + 1) * 64 + lane];
            }
            float area = ((v.z - v.x) + 1.f) * ((v.w - v.y) + 1.f);
            int Cm2 = s_cnt[k & 1];           // kept count through block k-2
            bool sup = !valid;
            int kk = Cm2;                      // delta: keeps added by block k-1 (unroll 2)
            for (; kk + 1 < Cm1; kk += 2) {
                float4 k0 = s_box[kk],   k1 = s_box[kk + 1];
                float  r0 = s_ar [kk],   r1 = s_ar [kk + 1];
                sup = sup | iou_gt(v, area, k0, r0) | iou_gt(v, area, k1, r1);
            }
            for (; kk < Cm1; ++kk)
                sup = sup | iou_gt(v, area, s_box[kk], s_ar[kk]);
            unsigned long long supm = __ballot(sup);
            const unsigned long long* pnd = s_pend[k & 1];
#pragma unroll
            for (int w2 = 1; w2 < 16; ++w2) supm |= pnd[w2];
            unsigned int rlo = (unsigned int)row;
            unsigned int rhi = (unsigned int)(row >> 32);
            unsigned long long alive = ~supm;
            unsigned long long keepm = 0ull;
            while (alive) {
                int i = __builtin_ctzll(alive);     // uniform across wave 0
                keepm |= (1ull << i);
                alive &= ~(1ull << i);
                unsigned long long mlo = (unsigned int)__builtin_amdgcn_readlane((int)rlo, i);
                unsigned long long mhi = (unsigned int)__builtin_amdgcn_readlane((int)rhi, i);
                alive &= ~((mhi << 32) | mlo);
            }
            if ((keepm >> lane) & 1ull) {
                int my = Cm1 + __builtin_popcountll(keepm & ((1ull << lane) - 1ull));
                s_box[my] = v;
                s_ar [my] = area;
                if (my < POST_) {
                    ob[my * 5 + 0] = (float)b;
                    ob[my * 5 + 1] = v.x; ob[my * 5 + 2] = v.y;
                    ob[my * 5 + 3] = v.z; ob[my * 5 + 4] = v.w;
                }
            }
            if (lane == 0) {
                int nc = Cm1 + __builtin_popcountll(keepm);
                s_cnt[k & 1] = nc;
                s_final = nc;
            }
        } else if (k + 1 < NB_) {
            // phase-a for block k+1 vs kept[0..Cm1), stride 15, UNROLLED x4
            int jdx = (k + 1) * 64 + lane;
            bool valid2 = jdx < PRE_;
            float4 v2 = vme;
            if (k + 2 < NB_) {                 // prefetch block k+2
                int nj = (k + 2) * 64 + lane;
                vme = bb[nj < PRE_ ? nj : PRE_ - 1];
            }
            float area2 = ((v2.z - v2.x) + 1.f) * ((v2.w - v2.y) + 1.f);
            bool sup2 = !valid2;
            int kk = wave - 1;
            for (; kk + 45 < Cm1; kk += 60) {   // 4 strided entries per pass
                float4 k0 = s_box[kk],      k1 = s_box[kk + 15];
                float4 k2 = s_box[kk + 30], k3 = s_box[kk + 45];
                float  r0 = s_ar [kk],      r1 = s_ar [kk + 15];
                float  r2 = s_ar [kk + 30], r3 = s_ar [kk + 45];
                sup2 = sup2 | iou_gt(v2, area2, k0, r0) | iou_gt(v2, area2, k1, r1)
                            | iou_gt(v2, area2, k2, r2) | iou_gt(v2, area2, k3, r3);
            }
            for (; kk < Cm1; kk += 15)
                sup2 = sup2 | iou_gt(v2, area2, s_box[kk], s_ar[kk]);
            unsigned long long bal = __ballot(sup2);
            if (lane == 0) s_pend[(k + 1) & 1][wave] = bal;
        }
        __syncthreads();
    }
    __syncthreads();
    int kept = s_final;
    int start = kept < POST_ ? kept : POST_;
    for (int r = start + tid; r < POST_; r += 1024) {
        ob[r * 5 + 0] = (float)b;
        ob[r * 5 + 1] = 0.f; ob[r * 5 + 2] = 0.f;
        ob[r * 5 + 3] = 0.f; ob[r * 5 + 4] = 0.f;
    }
}

extern "C" void kernel_launch(void* const* d_in, const int* in_sizes, int n_in,
                              void* d_out, int out_size, void* d_ws, size_t ws_size,
                              hipStream_t stream) {
    const float* scores  = (const float*)d_in[0];
    const float* deltas  = (const float*)d_in[1];
    const float* im_info = (const float*)d_in[2];
    float* out = (float*)d_out;

    // workspace layout. maskb OVERLAPS hist (hist dead after k_scatter; k_mask later).
    char* ws = (char*)d_ws;
    unsigned int*       hist    = (unsigned int*)      (ws);             // 262,144
    unsigned long long* maskb   = (unsigned long long*)(ws);             // 192,512 (reuse)
    unsigned int*       prefw   = (unsigned int*)      (ws + 262144);    // 262,144
    unsigned long long* skeys   = (unsigned long long*)(ws + 524288);    // 262,144
    unsigned int*       actA    = (unsigned int*)      (ws + 786432);    //   4,096
    unsigned int*       actB    = (unsigned int*)      (ws + 790528);    //   4,096
    unsigned int*       actcnt  = (unsigned int*)      (ws + 794624);    //      32
    float*              sbx     = (float*)             (ws + 794656);    // 384,000

    k_hp<<<B_, 1024, 0, stream>>>(scores, hist, prefw, actA, actB, actcnt);
    dim3 g2d((N_ + 255) / 256, B_);
    k_scatter<<<g2d, 256, 0, stream>>>(scores, hist, prefw, skeys);
    dim3 fgrid(ACTMAX, B_);
    k_fixup<<<fgrid, 256, 0, stream>>>(skeys, actA, actB, actcnt, deltas, im_info, sbx);
    dim3 mgrid(NB_, B_);
    k_mask<<<mgrid, 64, 0, stream>>>(sbx, maskb);
    k_nms<<<B_, 1024, 0, stream>>>(sbx, maskb, out);
}

// Round 15
// 81.738 us; speedup vs baseline: 2.5378x; 1.1064x over previous
//
#include <hip/hip_runtime.h>
#include <stdint.h>

#define B_     4
#define A_     9
#define H_     50
#define W_     76
#define HW_    (H_ * W_)         // 3800
#define N_     (HW_ * A_)        // 34200
#define PRE_   6000
#define POST_  300
#define NBIN   16384
#define BINOFF 0xC000
#define SKCAP  8192
#define ACTMAX 256
#define FXCAP  2048
#define NB_    94                // ceil(PRE_/64)

// generate_anchors(16) precomputed (exact, verified against the numpy code)
__constant__ float c_anchors[9][4] = {
    { -84.f,  -40.f,  99.f,  55.f},
    {-176.f,  -88.f, 191.f, 103.f},
    {-360.f, -184.f, 375.f, 199.f},
    { -56.f,  -56.f,  71.f,  71.f},
    {-120.f, -120.f, 135.f, 135.f},
    {-248.f, -248.f, 263.f, 263.f},
    { -36.f,  -80.f,  51.f,  95.f},
    { -80.f, -168.f,  95.f, 183.f},
    {-168.f, -344.f, 183.f, 359.f},
};

// scores in [0,1) -> bin = top16(~score_bits) - 0xC000, clamped (monotone; exactness is
// restored by full-key rank within bucket in k_fixup).
__device__ __forceinline__ int sb_bin(unsigned int sb) {
    int bin = (int)((~sb) >> 16) - BINOFF;
    return bin < 0 ? 0 : bin;
}

// ---- kernel 1: fused LDS histogram + prefix + scatter, ONE block per image.
//      (round-11's proven P1-P3: per-image dependency -> single workgroup, only
//      __syncthreads needed). Writes skeys + active-bucket list to global.
__global__ __launch_bounds__(1024) void k_hps(const float* __restrict__ scores,
                                              unsigned long long* __restrict__ skeys,
                                              unsigned int* __restrict__ actA,
                                              unsigned int* __restrict__ actB,
                                              unsigned int* __restrict__ actcnt) {
    const int b = blockIdx.x, tid = threadIdx.x;
    const int lane = tid & 63, wid = tid >> 6;
    __shared__ unsigned int LHIST[NBIN];    // 64 KB: hist -> exclusive prefix -> working
    __shared__ unsigned int s_wsum[16];
    __shared__ unsigned int s_aA[ACTMAX];
    __shared__ unsigned int s_aB[ACTMAX];
    __shared__ int s_actn, s_binhi;

    for (int i = tid; i < NBIN; i += 1024) LHIST[i] = 0u;
    if (tid == 0) { s_actn = 0; s_binhi = 0; }
    __syncthreads();

    // P1: LDS histogram (coalesced score reads)
    const float* sc = scores + (size_t)((b * 2 * A_) + A_) * HW_;
    for (int i = tid; i < N_; i += 1024) {
        unsigned int sb = __float_as_uint(sc[i]);
        atomicAdd(&LHIST[sb_bin(sb)], 1u);
    }
    __syncthreads();

    // P2: in-place exclusive prefix (16 bins/thread, hierarchical shfl scan),
    //     active-bucket list, bin_hi (prefix monotone -> active bins = [0, bin_hi])
    {
        int base0 = tid * 16;
        unsigned int sum = 0;
        for (int q = 0; q < 16; ++q) sum += LHIST[base0 + q];
        unsigned int inc = sum;
#pragma unroll
        for (int off = 1; off < 64; off <<= 1) {
            unsigned int t = __shfl_up(inc, off);
            if (lane >= off) inc += t;
        }
        if (lane == 63) s_wsum[wid] = inc;
        __syncthreads();
        unsigned int wbase = 0;
        for (int wq = 0; wq < wid; ++wq) wbase += s_wsum[wq];
        unsigned int run = wbase + inc - sum;     // exclusive prefix of this thread's bins
        int mybinhi = -1;
        for (int q = 0; q < 16; ++q) {
            unsigned int c = LHIST[base0 + q];
            LHIST[base0 + q] = run;
            if (run < (unsigned int)PRE_) {
                mybinhi = base0 + q;
                if (c > 0) {
                    int pos = atomicAdd(&s_actn, 1);
                    if (pos < ACTMAX) {
                        s_aA[pos] = run;
                        s_aB[pos] = ((unsigned int)(base0 + q) << 16) | (c & 0xffffu);
                    }
                }
            }
            run += c;
        }
        if (mybinhi >= 0) atomicMax(&s_binhi, mybinhi);
    }
    __syncthreads();

    // P3: scatter keys of active bins to global slot ranges (arrival order)
    {
        int binhi = s_binhi;
        for (int i = tid; i < N_; i += 1024) {
            unsigned int sb = __float_as_uint(sc[i]);
            int bin = sb_bin(sb);
            if (bin <= binhi) {
                unsigned int slot = atomicAdd(&LHIST[bin], 1u);
                if (slot < SKCAP) {
                    int a = i / HW_, r = i - a * HW_;
                    unsigned int n = (unsigned int)(r * A_ + a);
                    skeys[b * SKCAP + slot] =
                        (((unsigned long long)(~sb)) << 32) | (unsigned long long)n;
                }
            }
        }
    }
    // export active-bucket list (written in P2; sync above orders it)
    int n = s_actn; if (n > ACTMAX) n = ACTMAX;
    for (int i = tid; i < n; i += 1024) {
        actA[b * ACTMAX + i] = s_aA[i];
        actB[b * ACTMAX + i] = s_aB[i];
    }
    if (tid == 0) actcnt[b] = (unsigned int)n;
}

// box decode exactly in the reference op order; no FMA contraction
__device__ __forceinline__ void compute_box(int b, unsigned int n,
                                            const float* __restrict__ deltas,
                                            const float* __restrict__ im_info,
                                            float box[4]) {
#pragma clang fp contract(off)
    int a   = (int)(n % A_);
    int pos = (int)(n / A_);
    int w   = pos % W_;
    int h   = pos / W_;
    float a0 = c_anchors[a][0] + (float)(w * 16);
    float a1 = c_anchors[a][1] + (float)(h * 16);
    float a2 = c_anchors[a][2] + (float)(w * 16);
    float a3 = c_anchors[a][3] + (float)(h * 16);
    float wa  = a2 - a0 + 1.f;
    float ha  = a3 - a1 + 1.f;
    float cxa = a0 + 0.5f * wa;
    float cya = a1 + 0.5f * ha;
    int base = ((b * 4 * A_ + a * 4) * H_ + h) * W_ + w;
    const int chs = HW_;
    float dx = deltas[base];
    float dy = deltas[base + chs];
    float dw = deltas[base + 2 * chs];
    float dh = deltas[base + 3 * chs];
    float pcx = dx * wa + cxa;
    float pcy = dy * ha + cya;
    float pw  = expf(dw) * wa;
    float ph  = expf(dh) * ha;
    float x1 = pcx - 0.5f * pw;
    float y1 = pcy - 0.5f * ph;
    float x2 = pcx + 0.5f * pw;
    float y2 = pcy + 0.5f * ph;
    float imh = im_info[b * 3 + 0], imw = im_info[b * 3 + 1];
    x1 = fminf(fmaxf(x1, 0.f), imw - 1.f);
    x2 = fminf(fmaxf(x2, 0.f), imw - 1.f);
    y1 = fminf(fmaxf(y1, 0.f), imh - 1.f);
    y2 = fminf(fmaxf(y2, 0.f), imh - 1.f);
    box[0] = x1; box[1] = y1; box[2] = x2; box[3] = y2;
}

// ---- kernel 2: per-bucket exact rank-by-counting + box decode into final sorted slot
__global__ __launch_bounds__(256) void k_fixup(const unsigned long long* __restrict__ skeys,
                                               const unsigned int* __restrict__ actA,
                                               const unsigned int* __restrict__ actB,
                                               const unsigned int* __restrict__ actcnt,
                                               const float* __restrict__ deltas,
                                               const float* __restrict__ im_info,
                                               float* __restrict__ sboxes) {
    int b = blockIdx.y;
    unsigned int nact = actcnt[b];
    if (nact > ACTMAX) nact = ACTMAX;
    if (blockIdx.x >= nact) return;
    int tid = threadIdx.x;
    unsigned int start = actA[b * ACTMAX + blockIdx.x];
    unsigned int ab    = actB[b * ACTMAX + blockIdx.x];
    unsigned int cnt   = ab & 0xffffu;
    unsigned int m = cnt;
    if (start + m > SKCAP) m = SKCAP - start;
    if (m > FXCAP) m = FXCAP;
    __shared__ unsigned long long lk[FXCAP];   // 16 KB
    for (unsigned int i = tid; i < m; i += 256) lk[i] = skeys[b * SKCAP + start + i];
    __syncthreads();
    float4* sb4 = (float4*)sboxes;
    for (unsigned int e = tid; e < m; e += 256) {
        unsigned long long k = lk[e];
        unsigned int r = 0;
        for (unsigned int i = 0; i < m; ++i) r += (lk[i] < k) ? 1u : 0u;
        unsigned int pos = start + r;
        if (pos < (unsigned int)PRE_) {
            unsigned int n = (unsigned int)(k & 0xffffffffull);
            float box[4];
            compute_box(b, n, deltas, im_info, box);
            sb4[b * PRE_ + pos] = make_float4(box[0], box[1], box[2], box[3]);
        }
    }
}

__device__ __forceinline__ bool iou_gt(float4 p, float pa, float4 q, float qa) {
    float iw = fminf(p.z, q.z) - fmaxf(p.x, q.x) + 1.f;
    float ih = fminf(p.w, q.w) - fmaxf(p.y, q.y) + 1.f;
    iw = fmaxf(iw, 0.f); ih = fmaxf(ih, 0.f);
    float inter = iw * ih;
    float iou = inter / ((pa + qa) - inter);
    return iou > 0.7f;
}

// ---- kernel 3: exact greedy NMS, pipelined (round-7 structure) with IN-LOOP mask
//      generation. Per iteration k:
//        wave 0:  delta-check vs block k-1's new keeps, mask-resolve block k using
//                 LDS tile slot k%3, append/output.
//        waves 1-15: phase-a for block k+1 vs kept[0..Cm1), then build the 64x64
//                 diagonal mask tile for block k+2 (boxes already in vme) into
//                 slot (k+2)%3. Triple-buffered -> no intra-iteration race.
//      Prologue: waves 0-7 build tile 0, waves 8-15 build tile 1.
__global__ __launch_bounds__(1024) void k_nms(const float* __restrict__ sboxes,
                                              float* __restrict__ out) {
    int b = blockIdx.x;
    int tid = threadIdx.x;
    int lane = tid & 63;
    int wave = tid >> 6;                     // 0..15
    __shared__ float4 s_box[POST_ + 64];
    __shared__ float  s_ar [POST_ + 64];
    __shared__ unsigned long long s_pend[2][16];
    __shared__ unsigned long long s_mtile[3][64];   // triple-buffered mask tiles
    __shared__ int s_cnt[2];
    __shared__ int s_final;
    if (tid < 32) ((unsigned long long*)s_pend)[tid] = 0ull;
    if (tid < 2) s_cnt[tid] = 0;
    if (tid == 0) s_final = 0;

    const float4* bb = (const float4*)sboxes + b * PRE_;
    float* ob = out + b * POST_ * 5;

    // prologue: build mask tiles for blocks 0 (waves 0-7) and 1 (waves 8-15)
    {
        int blk01 = (wave < 8) ? 0 : 1;
        int wrel = wave & 7;
        float4 vb = bb[blk01 * 64 + lane];
        float ab = ((vb.z - vb.x) + 1.f) * ((vb.w - vb.y) + 1.f);
        for (int r = wrel * 8; r < wrel * 8 + 8; ++r) {
            float4 p;
            p.x = __shfl(vb.x, r); p.y = __shfl(vb.y, r);
            p.z = __shfl(vb.z, r); p.w = __shfl(vb.w, r);
            float pa = __shfl(ab, r);
            unsigned long long bal = __ballot((lane > r) && iou_gt(p, pa, vb, ab));
            if (lane == 0) s_mtile[blk01][r] = bal;
        }
    }
    // register prefetch: wave0 holds block 0; waves 1-15 hold block 1
    float4 vme;
    if (wave == 0) vme = bb[lane];
    else           vme = bb[64 + lane];
    __syncthreads();

    for (int k = 0; k < NB_; ++k) {
        int Cm1 = s_cnt[(k + 1) & 1];         // kept count through block k-1
        if (Cm1 >= POST_) break;
        if (wave == 0) {
            int idx = k * 64 + lane;
            bool valid = idx < PRE_;
            float4 v = vme;
            unsigned long long row = s_mtile[k % 3][lane];
            if (k + 1 < NB_) {                 // prefetch block k+1
                int nidx = (k + 1) * 64 + lane;
                vme = bb[nidx < PRE_ ? nidx : PRE_ - 1];
            }
            float area = ((v.z - v.x) + 1.f) * ((v.w - v.y) + 1.f);
            int Cm2 = s_cnt[k & 1];           // kept count through block k-2
            bool sup = !valid;
            int kk = Cm2;                      // delta: keeps added by block k-1
            for (; kk + 1 < Cm1; kk += 2) {
                float4 k0 = s_box[kk],   k1 = s_box[kk + 1];
                float  r0 = s_ar [kk],   r1 = s_ar [kk + 1];
                sup = sup | iou_gt(v, area, k0, r0) | iou_gt(v, area, k1, r1);
            }
            for (; kk < Cm1; ++kk)
                sup = sup | iou_gt(v, area, s_box[kk], s_ar[kk]);
            unsigned long long supm = __ballot(sup);
            const unsigned long long* pnd = s_pend[k & 1];
#pragma unroll
            for (int w2 = 1; w2 < 16; ++w2) supm |= pnd[w2];
            unsigned int rlo = (unsigned int)row;
            unsigned int rhi = (unsigned int)(row >> 32);
            unsigned long long alive = ~supm;
            unsigned long long keepm = 0ull;
            while (alive) {
                int i = __builtin_ctzll(alive);     // uniform across wave 0
                keepm |= (1ull << i);
                alive &= ~(1ull << i);
                unsigned long long mlo = (unsigned int)__builtin_amdgcn_readlane((int)rlo, i);
                unsigned long long mhi = (unsigned int)__builtin_amdgcn_readlane((int)rhi, i);
                alive &= ~((mhi << 32) | mlo);
            }
            if ((keepm >> lane) & 1ull) {
                int my = Cm1 + __builtin_popcountll(keepm & ((1ull << lane) - 1ull));
                s_box[my] = v;
                s_ar [my] = area;
                if (my < POST_) {
                    ob[my * 5 + 0] = (float)b;
                    ob[my * 5 + 1] = v.x; ob[my * 5 + 2] = v.y;
                    ob[my * 5 + 3] = v.z; ob[my * 5 + 4] = v.w;
                }
            }
            if (lane == 0) {
                int nc = Cm1 + __builtin_popcountll(keepm);
                s_cnt[k & 1] = nc;
                s_final = nc;
            }
        } else if (k + 1 < NB_) {
            // phase-a for block k+1 vs kept[0..Cm1), stride 15, unrolled x4
            int jdx = (k + 1) * 64 + lane;
            bool valid2 = jdx < PRE_;
            float4 v2 = vme;
            if (k + 2 < NB_) {                 // prefetch block k+2
                int nj = (k + 2) * 64 + lane;
                vme = bb[nj < PRE_ ? nj : PRE_ - 1];
            }
            float area2 = ((v2.z - v2.x) + 1.f) * ((v2.w - v2.y) + 1.f);
            bool sup2 = !valid2;
            int kk = wave - 1;
            for (; kk + 45 < Cm1; kk += 60) {
                float4 k0 = s_box[kk],      k1 = s_box[kk + 15];
                float4 k2 = s_box[kk + 30], k3 = s_box[kk + 45];
                float  r0 = s_ar [kk],      r1 = s_ar [kk + 15];
                float  r2 = s_ar [kk + 30], r3 = s_ar [kk + 45];
                sup2 = sup2 | iou_gt(v2, area2, k0, r0) | iou_gt(v2, area2, k1, r1)
                            | iou_gt(v2, area2, k2, r2) | iou_gt(v2, area2, k3, r3);
            }
            for (; kk < Cm1; kk += 15)
                sup2 = sup2 | iou_gt(v2, area2, s_box[kk], s_ar[kk]);
            unsigned long long bal = __ballot(sup2);
            if (lane == 0) s_pend[(k + 1) & 1][wave] = bal;
            // build mask tile for block k+2 (vme holds its boxes) into slot (k+2)%3
            if (k + 2 < NB_) {
                float amex = ((vme.z - vme.x) + 1.f) * ((vme.w - vme.y) + 1.f);
                int slot = (k + 2) % 3;
                for (int r = wave - 1; r < 64; r += 15) {
                    float4 p;
                    p.x = __shfl(vme.x, r); p.y = __shfl(vme.y, r);
                    p.z = __shfl(vme.z, r); p.w = __shfl(vme.w, r);
                    float pa = __shfl(amex, r);
                    unsigned long long mb = __ballot((lane > r) && iou_gt(p, pa, vme, amex));
                    if (lane == 0) s_mtile[slot][r] = mb;
                }
            }
        }
        __syncthreads();
    }
    __syncthreads();
    int kept = s_final;
    int start = kept < POST_ ? kept : POST_;
    for (int r = start + tid; r < POST_; r += 1024) {
        ob[r * 5 + 0] = (float)b;
        ob[r * 5 + 1] = 0.f; ob[r * 5 + 2] = 0.f;
        ob[r * 5 + 3] = 0.f; ob[r * 5 + 4] = 0.f;
    }
}

extern "C" void kernel_launch(void* const* d_in, const int* in_sizes, int n_in,
                              void* d_out, int out_size, void* d_ws, size_t ws_size,
                              hipStream_t stream) {
    const float* scores  = (const float*)d_in[0];
    const float* deltas  = (const float*)d_in[1];
    const float* im_info = (const float*)d_in[2];
    float* out = (float*)d_out;

    char* ws = (char*)d_ws;
    unsigned long long* skeys  = (unsigned long long*)(ws);            // 262,144
    unsigned int*       actA   = (unsigned int*)      (ws + 262144);   //   4,096
    unsigned int*       actB   = (unsigned int*)      (ws + 266240);   //   4,096
    unsigned int*       actcnt = (unsigned int*)      (ws + 270336);   //      32
    float*              sbx    = (float*)             (ws + 270368);   // 384,000

    k_hps<<<B_, 1024, 0, stream>>>(scores, skeys, actA, actB, actcnt);
    dim3 fgrid(ACTMAX, B_);
    k_fixup<<<fgrid, 256, 0, stream>>>(skeys, actA, actB, actcnt, deltas, im_info, sbx);
    k_nms<<<B_, 1024, 0, stream>>>(sbx, out);
}